// Round 11
// baseline (164.130 us; speedup 1.0000x reference)
//
#include <hip/hip_runtime.h>

#define T_DIM 8192
#define D_DIM 256
#define N_DIM 64
#define LOG2E 1.44269504f

typedef __bf16 bf16x8 __attribute__((ext_vector_type(8)));
typedef __bf16 bf16x4 __attribute__((ext_vector_type(4)));
typedef float f32x16 __attribute__((ext_vector_type(16)));

__device__ __forceinline__ f32x16 zero16() {
  f32x16 v;
#pragma unroll
  for (int i = 0; i < 16; ++i) v[i] = 0.f;
  return v;
}

// DHf: fragment-major. Row-group G=row>>5, chunk c=kk*2+h, lane l31:
// DHf[G*2048 + c*256 + l31*8 .. +7]; wave load = base + lane*16B, coalesced.
// Hbf_sw: per 64-t block tblk, [d][granule]: image granule (tb ^ swz(d))
// holds t-granule tb (8 bf16), swz(d) = (d^(d>>3))&7 — k_z's exact LDS image.

// ---------------------------------------------------------------------------
// K1: DHf (fragment-major) via split-bf16 MFMA + Hbf_sw (pre-swizzled bf16 H
//     image, UNSCALED) + lbe[t] + rowsum[t]=0. grid 128 x 256.
// ---------------------------------------------------------------------------
__global__ __launch_bounds__(256) void k_dh(const float* __restrict__ H,
                                            const float* __restrict__ Dm,
                                            __bf16* __restrict__ DHf,
                                            __bf16* __restrict__ Hbf_sw,
                                            float* __restrict__ lbe,
                                            float* __restrict__ rowsum) {
  __shared__ __bf16 HlThi[64 * 264];
  __shared__ __bf16 HlTlo[64 * 264];
  __shared__ __bf16 DHs[64 * 72];
  const int tid = threadIdx.x;
  const int t0 = blockIdx.x * 64;
  const int lane = tid & 63;
  const int wave = tid >> 6;
  const int h = lane >> 5;
  const int l31 = lane & 31;
  const float4* H4 = (const float4*)H;
#pragma unroll
  for (int r = 0; r < 16; ++r) {
    int idx = r * 256 + tid;
    int d = idx >> 4, tc = idx & 15;
    float4 v = H4[(size_t)d * (T_DIM / 4) + (t0 >> 2) + tc];
    float vv[4] = {v.x, v.y, v.z, v.w};
    bf16x4 whi;
#pragma unroll
    for (int i = 0; i < 4; ++i) {
      __bf16 hi = (__bf16)vv[i];
      float lo = vv[i] - (float)hi;
      whi[i] = hi;
      HlThi[(tc * 4 + i) * 264 + d] = hi;
      HlTlo[(tc * 4 + i) * 264 + d] = (__bf16)lo;
    }
    // emit pre-swizzled H image (k_scaleH eliminated): granule tb = tc>>1,
    // half-granule offset (tc&1)*4, dest granule tb ^ swz(d).
    int tb = tc >> 1, off = (tc & 1) * 4;
    int swz = (d ^ (d >> 3)) & 7;
    *(bf16x4*)(Hbf_sw + (size_t)blockIdx.x * 16384 + (size_t)d * 64 +
               ((tb ^ swz) << 3) + off) = whi;
  }
  __syncthreads();
  const int tt = wave & 1, nh = wave >> 1;
  const int m = tt * 32 + l31;
  const int n = nh * 32 + l31;
  f32x16 c = zero16();
  for (int kk = 0; kk < 16; ++kk) {
    bf16x8 ahi = *(const bf16x8*)&HlThi[m * 264 + kk * 16 + h * 8];
    bf16x8 alo = *(const bf16x8*)&HlTlo[m * 264 + kk * 16 + h * 8];
    const float4* dp = (const float4*)(Dm + (size_t)n * 256 + kk * 16 + h * 8);
    float4 b0 = dp[0], b1 = dp[1];
    float bv[8] = {b0.x, b0.y, b0.z, b0.w, b1.x, b1.y, b1.z, b1.w};
    bf16x8 bhi, blo;
#pragma unroll
    for (int i = 0; i < 8; ++i) {
      __bf16 hi = (__bf16)bv[i];
      bhi[i] = hi;
      blo[i] = (__bf16)(bv[i] - (float)hi);
    }
    c = __builtin_amdgcn_mfma_f32_32x32x16_bf16(ahi, bhi, c, 0, 0, 0);
    c = __builtin_amdgcn_mfma_f32_32x32x16_bf16(ahi, blo, c, 0, 0, 0);
    c = __builtin_amdgcn_mfma_f32_32x32x16_bf16(alo, bhi, c, 0, 0, 0);
  }
#pragma unroll
  for (int r = 0; r < 16; ++r) {
    int row = tt * 32 + (r & 3) + 8 * (r >> 2) + 4 * h;
    DHs[row * 72 + n] = (__bf16)c[r];
  }
  __syncthreads();
#pragma unroll
  for (int r = 0; r < 2; ++r) {
    int idx = r * 256 + tid;
    int g = idx >> 8, cc = (idx >> 5) & 7, l = idx & 31;
    bf16x8 w = *(const bf16x8*)&DHs[(g * 32 + l) * 72 + cc * 8];
    *(bf16x8*)(DHf + (size_t)(blockIdx.x * 2 + g) * 2048 + cc * 256 + l * 8) = w;
  }
  if (tid < 64) {
    float s = 0.f;
#pragma unroll
    for (int q = 0; q < 8; ++q) {
      bf16x8 w = *(const bf16x8*)&DHs[tid * 72 + q * 8];
#pragma unroll
      for (int i = 0; i < 8; ++i) { float f = (float)w[i]; s += f * f; }
    }
    lbe[t0 + tid] = -0.5f * s * LOG2E;
    rowsum[t0 + tid] = 0.f;
  }
}

// ---------------------------------------------------------------------------
// K2: rowsum[t] += sum_j exp(S+lb); also zeroes Z (1 float4/thread).
//     grid 2048 x 256; j-prefetch double-buffer (R7-style).
// ---------------------------------------------------------------------------
__global__ __launch_bounds__(256, 2) void k_rowsum(const __bf16* __restrict__ DHf,
                                                   const float* __restrict__ lbe,
                                                   float* __restrict__ rowsum,
                                                   float* __restrict__ Z) {
  __shared__ float red2[64 * 65];
  const int tid = threadIdx.x;
  const int lane = tid & 63;
  const int wave = tid >> 6;
  const int h = lane >> 5;
  const int tt = wave & 1, jt = wave >> 1;
  const int t0 = (int)(blockIdx.x >> 4) * 64;
  const int jbase = (int)(blockIdx.x & 15) * 512;
  const int Gt = (t0 >> 5) + tt;
  // Z zero: 2048 blocks x 256 thr x 16B = 8 MB exactly
  ((float4*)Z)[(size_t)blockIdx.x * 256 + tid] = float4{0.f, 0.f, 0.f, 0.f};
  bf16x8 aR[4];
#pragma unroll
  for (int kk = 0; kk < 4; ++kk)
    aR[kk] = *(const bf16x8*)(DHf + (size_t)Gt * 2048 + kk * 512 + lane * 8);
  float racc[16];
#pragma unroll
  for (int r = 0; r < 16; ++r) racc[r] = 0.f;
  bf16x8 bN[4];
  {
    const size_t Gj0 = (jbase >> 5) + jt;
#pragma unroll
    for (int kk = 0; kk < 4; ++kk)
      bN[kk] = *(const bf16x8*)(DHf + Gj0 * 2048 + kk * 512 + lane * 8);
  }
  for (int jit = 0; jit < 8; ++jit) {
    bf16x8 bC[4];
#pragma unroll
    for (int kk = 0; kk < 4; ++kk) bC[kk] = bN[kk];
    const float lbv = lbe[jbase + jit * 64 + jt * 32 + (lane & 31)];
    if (jit < 7) {
      const size_t Gj = (jbase >> 5) + (jit + 1) * 2 + jt;
#pragma unroll
      for (int kk = 0; kk < 4; ++kk)
        bN[kk] = *(const bf16x8*)(DHf + Gj * 2048 + kk * 512 + lane * 8);
    }
    f32x16 s = zero16();
#pragma unroll
    for (int kk = 0; kk < 4; ++kk)
      s = __builtin_amdgcn_mfma_f32_32x32x16_bf16(aR[kk], bC[kk], s, 0, 0, 0);
#pragma unroll
    for (int r = 0; r < 16; ++r)
      racc[r] += __builtin_amdgcn_exp2f(__builtin_fmaf(s[r], LOG2E, lbv));
  }
#pragma unroll
  for (int r = 0; r < 16; ++r) {
    int tl = tt * 32 + (r & 3) + 8 * (r >> 2) + 4 * h;
    red2[tl * 65 + jt * 32 + (lane & 31)] = racc[r];
  }
  __syncthreads();
  if (tid < 64) {
    float s = 0.f;
#pragma unroll 8
    for (int c = 0; c < 64; ++c) s += red2[tid * 65 + c];
    atomicAdd(&rowsum[t0 + tid], s);
  }
}

// ---------------------------------------------------------------------------
// K3: Z[d][j] += l2 * sum_t H[d][t] * E[t][j]*rinv[t]  (rinv folded into the
//     P-pack; H image unscaled). grid 512 = 64 j x 2 dh x 4 ts. One barrier
//     per iter, Hs+Pt double-buffered (64 KB), DMA drained a full iter later.
// ---------------------------------------------------------------------------
__global__ __launch_bounds__(256, 2) void k_z(const __bf16* __restrict__ Hbf_sw,
                                              const __bf16* __restrict__ DHf,
                                              const float* __restrict__ lbe,
                                              const float* __restrict__ rowsum,
                                              const float* __restrict__ l2p,
                                              float* __restrict__ Z) {
  __shared__ __bf16 Hs[2][128 * 64];  // 2 x 16 KB
  __shared__ __bf16 Pt[2][128 * 64];  // 2 x 16 KB
  const int tid = threadIdx.x;
  const int lane = tid & 63;
  const int wave = tid >> 6;
  const int h = lane >> 5;
  const int l31 = lane & 31;
  const int bx = blockIdx.x;
  const int ts = bx & 3;
  const int dh = (bx >> 2) & 1;
  const int j0 = (bx >> 3) * 128;
  const int tbase = ts * 2048;
  const float l2v = l2p[0];
  const int s_tt = wave & 1, s_jg = wave >> 1;
  bf16x8 bS[2][4];
  float lbv[2];
#pragma unroll
  for (int q = 0; q < 2; ++q) {
    const size_t Gj = (j0 >> 5) + s_jg * 2 + q;
#pragma unroll
    for (int kk = 0; kk < 4; ++kk)
      bS[q][kk] = *(const bf16x8*)(DHf + Gj * 2048 + kk * 512 + lane * 8);
    lbv[q] = lbe[j0 + (s_jg * 2 + q) * 32 + l31];
  }
  f32x16 acc[2][2];
#pragma unroll
  for (int u = 0; u < 2; ++u)
#pragma unroll
    for (int v = 0; v < 2; ++v) acc[u][v] = zero16();

#define DMA_HS(buf_, it_)                                                       \
  {                                                                             \
    const __bf16* gsrc =                                                        \
        Hbf_sw + (size_t)(ts * 32 + (it_)) * 16384 + (size_t)dh * 8192;         \
    _Pragma("unroll") for (int r = 0; r < 4; ++r) {                             \
      int chunk = wave * 4 + r;                                                 \
      __builtin_amdgcn_global_load_lds(                                         \
          (const __attribute__((address_space(1))) unsigned int*)(gsrc +        \
              chunk * 512 + lane * 8),                                          \
          (__attribute__((address_space(3))) unsigned int*)(&Hs[buf_][0] +      \
              chunk * 512),                                                     \
          16, 0, 0);                                                            \
    }                                                                           \
  }

  // rinv for tile it: rvv[g] = rcp(rowsum[tbase + it*64 + s_tt*32 + g*8+4h ..])
  float4 rvv[4];
#define LOAD_RVV(it_)                                                           \
  {                                                                             \
    _Pragma("unroll") for (int g = 0; g < 4; ++g) {                             \
      const float4 rs4 = *(const float4*)(rowsum + tbase + (it_) * 64 +         \
                                          s_tt * 32 + g * 8 + 4 * h);           \
      rvv[g].x = __builtin_amdgcn_rcpf(rs4.x);                                  \
      rvv[g].y = __builtin_amdgcn_rcpf(rs4.y);                                  \
      rvv[g].z = __builtin_amdgcn_rcpf(rs4.z);                                  \
      rvv[g].w = __builtin_amdgcn_rcpf(rs4.w);                                  \
    }                                                                           \
  }

#define S_PHASE(p_)                                                             \
  {                                                                             \
    _Pragma("unroll") for (int q = 0; q < 2; ++q) {                             \
      f32x16 s = zero16();                                                      \
      _Pragma("unroll") for (int kk = 0; kk < 4; ++kk)                          \
          s = __builtin_amdgcn_mfma_f32_32x32x16_bf16(aR[kk], bS[q][kk], s, 0,  \
                                                      0, 0);                    \
      const int jl = (s_jg * 2 + q) * 32 + l31;                                 \
      const int sj = (jl ^ (jl >> 3)) & 7;                                      \
      _Pragma("unroll") for (int g = 0; g < 4; ++g) {                           \
        const int tl = s_tt * 32 + g * 8 + 4 * h;                               \
        bf16x4 pv;                                                              \
        pv[0] = (__bf16)(__builtin_amdgcn_exp2f(                                \
                    __builtin_fmaf(s[g * 4 + 0], LOG2E, lbv[q])) * rvv[g].x);   \
        pv[1] = (__bf16)(__builtin_amdgcn_exp2f(                                \
                    __builtin_fmaf(s[g * 4 + 1], LOG2E, lbv[q])) * rvv[g].y);   \
        pv[2] = (__bf16)(__builtin_amdgcn_exp2f(                                \
                    __builtin_fmaf(s[g * 4 + 2], LOG2E, lbv[q])) * rvv[g].z);   \
        pv[3] = (__bf16)(__builtin_amdgcn_exp2f(                                \
                    __builtin_fmaf(s[g * 4 + 3], LOG2E, lbv[q])) * rvv[g].w);   \
        const int cchunk = tl >> 3;                                             \
        *(bf16x4*)&Pt[p_][jl * 64 + ((cchunk ^ sj) << 3) + 4 * h] = pv;         \
      }                                                                         \
    }                                                                           \
  }

  bf16x8 aR[4];
#pragma unroll
  for (int kk = 0; kk < 4; ++kk)
    aR[kk] = *(const bf16x8*)(DHf + (size_t)(ts * 64 + s_tt) * 2048 + kk * 512 + lane * 8);
  LOAD_RVV(0);
  DMA_HS(0, 0);
  S_PHASE(0);
#pragma unroll
  for (int kk = 0; kk < 4; ++kk)
    aR[kk] = *(const bf16x8*)(DHf + (size_t)(ts * 64 + 2 + s_tt) * 2048 + kk * 512 + lane * 8);
  LOAD_RVV(1);
  __syncthreads();  // Hs[0] drained, Pt[0] visible

  for (int it = 0; it < 32; ++it) {
    const int p = it & 1;
    if (it < 31) {
      DMA_HS(p ^ 1, it + 1);
      S_PHASE(p ^ 1);  // consumes aR/rvv = (it+1)
    }
    if (it < 30) {
      const size_t Gt = ts * 64 + (it + 2) * 2 + s_tt;
#pragma unroll
      for (int kk = 0; kk < 4; ++kk)
        aR[kk] = *(const bf16x8*)(DHf + Gt * 2048 + kk * 512 + lane * 8);
      LOAD_RVV(it + 2);
    }
    // ---- Z phase from buffers p ----
#pragma unroll
    for (int kk = 0; kk < 4; ++kk) {
      const int c = kk * 2 + h;
      bf16x8 af[2], bw[2];
#pragma unroll
      for (int u = 0; u < 2; ++u) {
        int dl = (wave & 1) * 64 + u * 32 + l31;
        af[u] = *(const bf16x8*)&Hs[p][dl * 64 + ((c ^ ((dl ^ (dl >> 3)) & 7)) << 3)];
      }
#pragma unroll
      for (int v = 0; v < 2; ++v) {
        int j = (wave >> 1) * 64 + v * 32 + l31;
        bw[v] = *(const bf16x8*)&Pt[p][j * 64 + ((c ^ ((j ^ (j >> 3)) & 7)) << 3)];
      }
#pragma unroll
      for (int u = 0; u < 2; ++u)
#pragma unroll
        for (int v = 0; v < 2; ++v)
          acc[u][v] = __builtin_amdgcn_mfma_f32_32x32x16_bf16(af[u], bw[v], acc[u][v], 0, 0, 0);
    }
    __syncthreads();
  }
#undef S_PHASE
#undef LOAD_RVV
#undef DMA_HS
#pragma unroll
  for (int u = 0; u < 2; ++u)
#pragma unroll
    for (int v = 0; v < 2; ++v)
#pragma unroll
      for (int r = 0; r < 16; ++r) {
        int d = dh * 128 + (wave & 1) * 64 + u * 32 + (r & 3) + 8 * (r >> 2) + 4 * h;
        int j = j0 + (wave >> 1) * 64 + v * 32 + l31;
        atomicAdd(&Z[(size_t)d * T_DIM + j], acc[u][v][r] * l2v);
      }
}

// ---------------------------------------------------------------------------
extern "C" void kernel_launch(void* const* d_in, const int* in_sizes, int n_in,
                              void* d_out, int out_size, void* d_ws,
                              size_t ws_size, hipStream_t stream) {
  (void)in_sizes; (void)n_in; (void)out_size; (void)ws_size;
  const float* H = (const float*)d_in[0];
  const float* Dm = (const float*)d_in[1];
  const float* l2 = (const float*)d_in[2];
  float* Z = (float*)d_out;
  char* ws = (char*)d_ws;
  __bf16* DHf = (__bf16*)ws;                        // 1,048,576 B
  float* lbe = (float*)(ws + 1048576);              // 32,768 B
  float* rowsum = (float*)(ws + 1048576 + 32768);   // 32,768 B
  __bf16* Hbf_sw = (__bf16*)(ws + 1048576 + 65536); // 4,194,304 B

  k_dh<<<128, 256, 0, stream>>>(H, Dm, DHf, Hbf_sw, lbe, rowsum);
  k_rowsum<<<2048, 256, 0, stream>>>(DHf, lbe, rowsum, Z);
  k_z<<<512, 256, 0, stream>>>(Hbf_sw, DHf, lbe, rowsum, l2, Z);
}